// Round 1
// baseline (15589.941 us; speedup 1.0000x reference)
//
#include <hip/hip_runtime.h>
#include <math.h>

#define B_ 32
#define S_ 128
#define H_ 512
#define V_ 32000
#define G4_ 2048
#define KS_ 16   // k-split for gates partials
#define KL_ 4    // k-split for logits partials

__device__ __forceinline__ float4 ldf4(const float* p) {
    return *reinterpret_cast<const float4*>(p);
}

// ---------------- init: copy h0, c0 into state buffers ----------------
__global__ __launch_bounds__(256) void k_init(float* __restrict__ h, float* __restrict__ c,
                                              const float* __restrict__ h0,
                                              const float* __restrict__ c0) {
    int i = blockIdx.x * 256 + threadIdx.x;
    h[i] = h0[i];
    c[i] = c0[i];
}

// ---------------- precompute XW[t][b][j] = emb[tok[b,t]] @ W_ih^T + b_ih + b_hh ----
// grid (8, 128): blockIdx.x covers j in 256-chunks, blockIdx.y = t. 4 waves/block,
// each wave owns 64 j's (lane = j), accumulates over all 32 batch rows.
__global__ __launch_bounds__(256) void k_xw(const int* __restrict__ inputs,
                                            const float* __restrict__ emb,
                                            const float* __restrict__ W_ih,
                                            const float* __restrict__ b_ih,
                                            const float* __restrict__ b_hh,
                                            float* __restrict__ XW) {
    const int lane = threadIdx.x & 63, w = threadIdx.x >> 6;
    const int j = blockIdx.x * 256 + w * 64 + lane;
    const int t = blockIdx.y;
    int tk[B_];
#pragma unroll
    for (int b = 0; b < B_; ++b) tk[b] = inputs[b * S_ + t];
    float acc[B_];
#pragma unroll
    for (int b = 0; b < B_; ++b) acc[b] = 0.f;
    for (int k = 0; k < H_; k += 4) {
        float4 wv = ldf4(W_ih + (size_t)j * H_ + k);
#pragma unroll
        for (int b = 0; b < B_; ++b) {
            float4 xv = ldf4(emb + (size_t)tk[b] * H_ + k);  // wave-uniform -> s_load
            acc[b] += wv.x * xv.x + wv.y * xv.y + wv.z * xv.z + wv.w * xv.w;
        }
    }
    const float bias = b_ih[j] + b_hh[j];
#pragma unroll
    for (int b = 0; b < B_; ++b)
        XW[(size_t)(t * B_ + b) * G4_ + j] = acc[b] + bias;
}

// ---------------- gates partials: gp[ks][b][j] = sum_{k in seg ks} h[b][k]*W_hh[j][k] ---
// 128 logical blocks: gblk%8 -> j 256-chunk (4 waves), gblk/8 -> k segment (32 k).
__device__ __forceinline__ void gates_body(int gblk, int w, int lane,
                                           const float* __restrict__ W_hh,
                                           const float* __restrict__ h,
                                           float* __restrict__ gp) {
    const int j = ((gblk & 7) * 4 + w) * 64 + lane;
    const int ks = gblk >> 3;
    const int k0 = ks * 32;
    float acc[B_];
#pragma unroll
    for (int b = 0; b < B_; ++b) acc[b] = 0.f;
#pragma unroll
    for (int kk = 0; kk < 32; kk += 4) {
        float4 wv = ldf4(W_hh + (size_t)j * H_ + k0 + kk);
#pragma unroll
        for (int b = 0; b < B_; ++b) {
            float4 hv = ldf4(h + b * H_ + k0 + kk);  // wave-uniform -> s_load
            acc[b] += wv.x * hv.x + wv.y * hv.y + wv.z * hv.z + wv.w * hv.w;
        }
    }
#pragma unroll
    for (int b = 0; b < B_; ++b)
        gp[(size_t)(ks * B_ + b) * G4_ + j] = acc[b];
}

__global__ __launch_bounds__(256) void k_gates(const float* __restrict__ W_hh,
                                               const float* __restrict__ h,
                                               float* __restrict__ gp) {
    gates_body(blockIdx.x, threadIdx.x >> 6, threadIdx.x & 63, W_hh, h, gp);
}

// ---------------- LSTM cell: reduce partials, activations, update h/c ----------
__global__ __launch_bounds__(256) void k_cell(const float* __restrict__ XW,
                                              const float* __restrict__ gp,
                                              float* __restrict__ h,
                                              float* __restrict__ c, int t) {
    const int b = blockIdx.x >> 1;
    const int n = ((blockIdx.x & 1) << 8) + threadIdx.x;
    float g4[4];
#pragma unroll
    for (int gi = 0; gi < 4; ++gi) {
        const int j = gi * H_ + n;
        float s = XW[(size_t)(t * B_ + b) * G4_ + j];
#pragma unroll
        for (int ks = 0; ks < KS_; ++ks) s += gp[(size_t)(ks * B_ + b) * G4_ + j];
        g4[gi] = s;
    }
    const float ig = 1.f / (1.f + expf(-g4[0]));
    const float fg = 1.f / (1.f + expf(-g4[1]));
    const float gg = tanhf(g4[2]);
    const float og = 1.f / (1.f + expf(-g4[3]));
    const float cn = fg * c[b * H_ + n] + ig * gg;
    c[b * H_ + n] = cn;
    h[b * H_ + n] = og * tanhf(cn);
}

// ---------------- logits partials: lp[ks][b][v] = sum_{k in seg} h[b][k]*W_out[v][k] ---
// grid 500 blocks x 256: lane = v (64 v per block), wave = k segment (128 k).
// Each lane accumulates all 32 b -> W_out read exactly once per step.
__global__ __launch_bounds__(256) void k_logits(const float* __restrict__ W_out,
                                                const float* __restrict__ h,
                                                float* __restrict__ lp) {
    const int lane = threadIdx.x & 63, wv_ = threadIdx.x >> 6;
    const int v = blockIdx.x * 64 + lane;
    const int k0 = wv_ * 128;
    float acc[B_];
#pragma unroll
    for (int b = 0; b < B_; ++b) acc[b] = 0.f;
    for (int kk = 0; kk < 128; kk += 4) {
        float4 w4 = ldf4(W_out + (size_t)v * H_ + k0 + kk);
#pragma unroll
        for (int b = 0; b < B_; ++b) {
            float4 hv = ldf4(h + b * H_ + k0 + kk);  // wave-uniform -> s_load
            acc[b] += w4.x * hv.x + w4.y * hv.y + w4.z * hv.z + w4.w * hv.w;
        }
    }
#pragma unroll
    for (int b = 0; b < B_; ++b)
        lp[(size_t)(wv_ * B_ + b) * V_ + v] = acc[b];
}

// ---------------- per-(b, v-chunk) online softmax/argmax/target partials -------
__device__ void soft_body(int sblk, int tid, const int* __restrict__ inputs,
                          const float* __restrict__ b_out, const float* __restrict__ lp,
                          float* __restrict__ sp, int t) {
    const int b = sblk >> 3, ch = sblk & 7;
    const int tok = inputs[b * S_ + t];
    float m = -INFINITY, s = 0.f, mv = -INFINITY, tv = -INFINITY;
    int mi = 0x7fffffff;
    const int v0 = ch * 4000, v1 = v0 + 4000;
    for (int v = v0 + tid; v < v1; v += 256) {
        float x = b_out[v]
                + lp[(size_t)(0 * B_ + b) * V_ + v]
                + lp[(size_t)(1 * B_ + b) * V_ + v]
                + lp[(size_t)(2 * B_ + b) * V_ + v]
                + lp[(size_t)(3 * B_ + b) * V_ + v];
        float nm = fmaxf(m, x);
        s = s * expf(m - nm) + expf(x - nm);
        m = nm;
        if (x > mv) { mv = x; mi = v; }   // strictly >, v ascending -> first occurrence
        if (v == tok) tv = x;
    }
    __shared__ float sm[256], ss[256], smv[256], stv[256];
    __shared__ int smi[256];
    sm[tid] = m; ss[tid] = s; smv[tid] = mv; smi[tid] = mi; stv[tid] = tv;
    __syncthreads();
    for (int off = 128; off > 0; off >>= 1) {
        if (tid < off) {
            float cm = sm[tid + off], cs = ss[tid + off];
            float cmv = smv[tid + off], ctv = stv[tid + off];
            int cmi = smi[tid + off];
            float nm = fmaxf(sm[tid], cm);
            ss[tid] = ss[tid] * expf(sm[tid] - nm) + cs * expf(cm - nm);
            sm[tid] = nm;
            if (cmv > smv[tid] || (cmv == smv[tid] && cmi < smi[tid])) {
                smv[tid] = cmv; smi[tid] = cmi;
            }
            stv[tid] = fmaxf(stv[tid], ctv);
        }
        __syncthreads();
    }
    if (tid == 0) {
        float* o = sp + ((size_t)(t * B_ + b) * 8 + ch) * 5;
        o[0] = sm[0]; o[1] = ss[0]; o[2] = smv[0]; o[3] = (float)smi[0]; o[4] = stv[0];
    }
}

// softmax chunks for step t (blocks 0..255) + gates partials for step t+1 (blocks 256..383)
__global__ __launch_bounds__(256) void k_soft_gates(const int* __restrict__ inputs,
                                                    const float* __restrict__ b_out,
                                                    const float* __restrict__ lp,
                                                    float* __restrict__ sp, int t,
                                                    const float* __restrict__ W_hh,
                                                    const float* __restrict__ h,
                                                    float* __restrict__ gp, int do_gates) {
    if (blockIdx.x < 256) {
        soft_body(blockIdx.x, threadIdx.x, inputs, b_out, lp, sp, t);
    } else if (do_gates) {
        gates_body(blockIdx.x - 256, threadIdx.x >> 6, threadIdx.x & 63, W_hh, h, gp);
    }
}

// ---------------- final: merge chunk partials, write symbols + loss ------------
__global__ __launch_bounds__(256) void k_final(const float* __restrict__ sp,
                                               float* __restrict__ out) {
    const int tid = threadIdx.x;
    float lsum = 0.f;
    for (int p = tid; p < B_ * S_; p += 256) {  // p = t*32 + b
        const int t = p >> 5, b = p & 31;
        const float* base = sp + (size_t)p * 8 * 5;
        float m = -INFINITY, s = 0.f, mv = -INFINITY, tv = -INFINITY, mi = 3.4e38f;
#pragma unroll
        for (int ch = 0; ch < 8; ++ch) {
            const float* o = base + ch * 5;
            float cm = o[0], cs = o[1], cmv = o[2], cmi = o[3], ctv = o[4];
            float nm = fmaxf(m, cm);
            s = s * expf(m - nm) + cs * expf(cm - nm);
            m = nm;
            if (cmv > mv || (cmv == mv && cmi < mi)) { mv = cmv; mi = cmi; }
            tv = fmaxf(tv, ctv);
        }
        const float logZ = m + logf(s);
        out[1 + b * S_ + t] = mi;          // symbols as float values
        lsum += tv - logZ;                 // logp at target token
    }
    __shared__ float red[256];
    red[tid] = lsum;
    __syncthreads();
    for (int off = 128; off > 0; off >>= 1) {
        if (tid < off) red[tid] += red[tid + off];
        __syncthreads();
    }
    if (tid == 0) out[0] = -red[0] / (float)B_;
}

extern "C" void kernel_launch(void* const* d_in, const int* in_sizes, int n_in,
                              void* d_out, int out_size, void* d_ws, size_t ws_size,
                              hipStream_t stream) {
    const int*   inputs = (const int*)d_in[0];
    // d_in[1] encoder_outputs, d_in[2] lengths: unused by the reference
    const float* h0     = (const float*)d_in[3];
    const float* c0     = (const float*)d_in[4];
    const float* emb    = (const float*)d_in[5];
    const float* W_ih   = (const float*)d_in[6];
    const float* W_hh   = (const float*)d_in[7];
    const float* b_ih   = (const float*)d_in[8];
    const float* b_hh   = (const float*)d_in[9];
    const float* W_out  = (const float*)d_in[10];
    const float* b_out  = (const float*)d_in[11];
    float* out = (float*)d_out;

    float* ws = (float*)d_ws;
    const size_t XW_N = (size_t)S_ * B_ * G4_;      // 8,388,608
    const size_t HC_N = (size_t)B_ * H_;            // 16,384
    const size_t GP_N = (size_t)KS_ * B_ * G4_;     // 1,048,576
    const size_t LP_N = (size_t)KL_ * B_ * V_;      // 4,096,000
    float* XW = ws;
    float* h  = XW + XW_N;
    float* c  = h + HC_N;
    float* gp = c + HC_N;
    float* lp = gp + GP_N;
    float* sp = lp + LP_N;                          // 128*32*8*5 = 163,840

    k_init<<<64, 256, 0, stream>>>(h, c, h0, c0);
    k_xw<<<dim3(8, 128), 256, 0, stream>>>(inputs, emb, W_ih, b_ih, b_hh, XW);
    k_gates<<<128, 256, 0, stream>>>(W_hh, h, gp);
    for (int t = 0; t < S_; ++t) {
        k_cell<<<64, 256, 0, stream>>>(XW, gp, h, c, t);
        k_logits<<<500, 256, 0, stream>>>(W_out, h, lp);
        k_soft_gates<<<384, 256, 0, stream>>>(inputs, b_out, lp, sp, t,
                                              W_hh, h, gp, (t < S_ - 1) ? 1 : 0);
    }
    k_final<<<1, 256, 0, stream>>>(sp, out);
}